// Round 7
// baseline (640.565 us; speedup 1.0000x reference)
//
#include <hip/hip_runtime.h>

#define TT 128
#define SS 512
#define START_TAG 126
#define STOP_TAG 127
#define LOG2E 1.4426950408889634f
#define LN2   0.6931471805599453f
#define CBITS 8

typedef float f32x4 __attribute__((ext_vector_type(4)));
typedef __fp16 f16x8 __attribute__((ext_vector_type(8)));
typedef __fp16 h2    __attribute__((ext_vector_type(2)));
typedef unsigned int u32;
typedef unsigned int u32x2 __attribute__((ext_vector_type(2)));
typedef unsigned int u32x4 __attribute__((ext_vector_type(4)));

__device__ __forceinline__ float ex2(float x){ return __builtin_amdgcn_exp2f(x); }   // 2^x
__device__ __forceinline__ float lg2(float x){ return __builtin_amdgcn_logf(x); }    // log2
__device__ __forceinline__ float exn(float x){ return __builtin_amdgcn_exp2f(x*LOG2E); } // e^x
__device__ __forceinline__ u32 pkh(float a, float b){
    return __builtin_bit_cast(u32, __builtin_amdgcn_cvt_pkrtz(a, b));
}
__device__ __forceinline__ float wave_max(float v) {
#pragma unroll
    for (int off = 32; off >= 1; off >>= 1) v = fmaxf(v, __shfl_xor(v, off));
    return v;
}
__device__ __forceinline__ float wave_sum(float v) {
#pragma unroll
    for (int off = 32; off >= 1; off >>= 1) v += __shfl_xor(v, off);
    return v;
}

// ---------------- pre-pass: ef[b][s][tag] = (f16) exp(feats) ----------------
__global__ __launch_bounds__(256) void exp_feats_kernel(
    const float* __restrict__ feats, __fp16* __restrict__ ef)
{
    size_t i = ((size_t)blockIdx.x * 256 + threadIdx.x) * 8;
    f32x4 a = *(const f32x4*)(feats + i);
    f32x4 b = *(const f32x4*)(feats + i + 4);
    u32x4 pk;
    pk[0] = pkh(exn(a[0]), exn(a[1]));
    pk[1] = pkh(exn(a[2]), exn(a[3]));
    pk[2] = pkh(exn(b[0]), exn(b[1]));
    pk[3] = pkh(exn(b[2]), exn(b[3]));
    *(u32x4*)(ef + i) = pk;
}

// E fragment builders (init-time only). k-map: k(q,h,j) = 32q + 16*(j>=4) + 4h + (j&3)
__device__ __forceinline__ f16x8 mkEf(const float* p) {          // fwd: rows contiguous
    f32x4 a = *(const f32x4*)p;
    f32x4 b = *(const f32x4*)(p + 16);
    u32x4 r = { pkh(exn(a[0]), exn(a[1])), pkh(exn(a[2]), exn(a[3])),
                pkh(exn(b[0]), exn(b[1])), pkh(exn(b[2]), exn(b[3])) };
    return __builtin_bit_cast(f16x8, r);
}
__device__ __forceinline__ f16x8 mkEb(const float* p) {          // bwd: E^T, stride-TT
    const float* q = p + 16 * TT;
    u32x4 r = { pkh(exn(p[0]), exn(p[TT])), pkh(exn(p[2*TT]), exn(p[3*TT])),
                pkh(exn(q[0]), exn(q[TT])), pkh(exn(q[2*TT]), exn(q[3*TT])) };
    return __builtin_bit_cast(f16x8, r);
}

// ---- macro lists: everything hot is a NAMED scalar (no C-arrays; R3/R4/R6
// showed LLVM parks arrays in the AGPR half -> accvgpr churn). ----
#define T8(M)    M(0) M(1) M(2) M(3) M(4) M(5) M(6) M(7)
#define T8P(M,P) M(0,P) M(1,P) M(2,P) M(3,P) M(4,P) M(5,P) M(6,P) M(7,P)

#define DECLE(t)  f16x8 E0##t, E1##t, E2##t, E3##t;
#define DECLEF(t) u32x2 EA##t, EB##t;
#define DECLS(t)  f32x4 S##t;
#define DECLA(t)  f32x4 A##t;

#define MFQ0(t) A##t = __builtin_amdgcn_mfma_f32_16x16x32_f16(E0##t, B0, vz,    0, 0, 0);
#define MFQ1(t) A##t = __builtin_amdgcn_mfma_f32_16x16x32_f16(E1##t, B1, A##t, 0, 0, 0);
#define MFQ2(t) A##t = __builtin_amdgcn_mfma_f32_16x16x32_f16(E2##t, B2, A##t, 0, 0, 0);
#define MFQ3(t) A##t = __builtin_amdgcn_mfma_f32_16x16x32_f16(E3##t, B3, A##t, 0, 0, 0);

// scale (f32 mul) -> f16 pack -> emission via v_pk_mul_f16 (ef prepassed).
// colmax tracked in f32 PRE-emission (avoids f16-denorm feedback corner).
#define PACKT(t, RR) { \
    float d0 = A##t[0]*scf, d1 = A##t[1]*scf, d2 = A##t[2]*scf, d3 = A##t[3]*scf; \
    mloc = fmaxf(fmaxf(mloc, fmaxf(d0, d1)), fmaxf(d2, d3)); \
    h2 x01 = __builtin_amdgcn_cvt_pkrtz(d0, d1) * __builtin_bit_cast(h2, RR##t[0]); \
    h2 x23 = __builtin_amdgcn_cvt_pkrtz(d2, d3) * __builtin_bit_cast(h2, RR##t[1]); \
    Pa##t = __builtin_bit_cast(u32, x01); Pb##t = __builtin_bit_cast(u32, x23); }

#define LDRT(t, RR) { if constexpr (PRE) { RR##t = *(const u32x2*)(pef + 32*(t)); } \
    else { f32x4 v_ = *(const f32x4*)(pef + 64*(t)); \
           RR##t[0] = pkh(exn(v_[0]), exn(v_[1])); RR##t[1] = pkh(exn(v_[2]), exn(v_[3])); } }
#define LDALL(RR) { T8P(LDRT, RR) pef += sstep; }

// One recurrence step for 16 chains. Scale 2^-s from LAG-1 post-scale colmax
// (stable: no feedback recurrence; validated R3/R4/R6). Integer-exact Mint.
#define MSTEP(RR) { \
    int s_ = ((__float_as_int(fmaxf(mprev, 1e-30f)) >> 23) & 255) - 126 + CBITS; \
    s_ = s_ < -120 ? -120 : (s_ > 120 ? 120 : s_); \
    Mint += s_; \
    const float scf = __int_as_float((127 - s_) << 23); \
    f32x4 vz = {0.f, 0.f, 0.f, 0.f}; \
    T8(DECLA) \
    __builtin_amdgcn_s_setprio(1); \
    T8(MFQ0) T8(MFQ1) T8(MFQ2) T8(MFQ3) \
    __builtin_amdgcn_s_setprio(0); \
    float mloc = 0.f; \
    u32 Pa0, Pa1, Pa2, Pa3, Pa4, Pa5, Pa6, Pa7; \
    u32 Pb0, Pb1, Pb2, Pb3, Pb4, Pb5, Pb6, Pb7; \
    T8P(PACKT, RR) \
    u32x4 b0_ = {Pa0, Pb0, Pa1, Pb1}; u32x4 b1_ = {Pa2, Pb2, Pa3, Pb3}; \
    u32x4 b2_ = {Pa4, Pb4, Pa5, Pb5}; u32x4 b3_ = {Pa6, Pb6, Pa7, Pb7}; \
    B0 = __builtin_bit_cast(f16x8, b0_); B1 = __builtin_bit_cast(f16x8, b1_); \
    B2 = __builtin_bit_cast(f16x8, b2_); B3 = __builtin_bit_cast(f16x8, b3_); \
    LDALL(RR) \
    mloc = fmaxf(mloc, __shfl_xor(mloc, 16)); \
    mloc = fmaxf(mloc, __shfl_xor(mloc, 32)); \
    mprev = mloc; }

#define EINF(t) { const float* rp = trans + (16*(t) + c) * TT + 4 * h; \
    E0##t = mkEf(rp); E1##t = mkEf(rp + 32); E2##t = mkEf(rp + 64); E3##t = mkEf(rp + 96); }
#define EINB(t) { const float* cp = trans + (4 * h) * TT + 16*(t) + c; \
    E0##t = mkEb(cp); E1##t = mkEb(cp + 32*TT); E2##t = mkEb(cp + 64*TT); E3##t = mkEb(cp + 96*TT); }

#define SEEDF(t) S##t = (f32x4){0.f, 0.f, 0.f, 0.f};
#define SEEDB(t) { \
    f32x4 tr4 = *(const f32x4*)(trans + STOP_TAG * TT + 16*(t) + 4*h); \
    f32x4 fe4 = *(const f32x4*)(feats + f511 + 16*(t) + 4*h); \
    S##t[0] = exn(tr4[0] + fe4[0]); S##t[1] = exn(tr4[1] + fe4[1]); \
    S##t[2] = exn(tr4[2] + fe4[2]); S##t[3] = exn(tr4[3] + fe4[3]); }
#define SMXT(t) smax = fmaxf(smax, fmaxf(fmaxf(S##t[0], S##t[1]), fmaxf(S##t[2], S##t[3])));
#define SPKT(t) { Pa##t = pkh(S##t[0]*sc0, S##t[1]*sc0); Pb##t = pkh(S##t[2]*sc0, S##t[3]*sc0); }

#define EPIT(t) { f32x4 v; \
    float e0 = 1.f, e1 = 1.f, e2 = 1.f, e3 = 1.f; \
    if (isFwd) { h2 a = __builtin_bit_cast(h2, EB##t[0]); h2 b = __builtin_bit_cast(h2, EB##t[1]); \
                 e0 = (float)a[0]; e1 = (float)a[1]; e2 = (float)b[0]; e3 = (float)b[1]; } \
    v[0] = Mtotf + lg2(fmaxf(A##t[0] * e0, 1e-35f)); \
    v[1] = Mtotf + lg2(fmaxf(A##t[1] * e1, 1e-35f)); \
    v[2] = Mtotf + lg2(fmaxf(A##t[2] * e2, 1e-35f)); \
    v[3] = Mtotf + lg2(fmaxf(A##t[3] * e3, 1e-35f)); \
    *(f32x4*)&AB[side][bb][16*(t) + 4*h] = v; }

// 4 blocks x 512 threads (8 waves = 2 per SIMD: TLP fills the phase-serial
// stalls R6 measured ~1100 cy/step of). Block k: batches 64k..64k+63.
//  w0-3: fwd chains (16 batches each)   w4-7: bwd chains (same batches)
template<bool PRE>
__global__ __launch_bounds__(512, 2) void crf_chain_kernel(
    const float* __restrict__ feats,
    const float* __restrict__ trans,
    const int*   __restrict__ targets,
    const __fp16* __restrict__ efeat,
    float*       __restrict__ out)
{
    const int t = threadIdx.x;
    const int w = t >> 6, l = t & 63;
    const int c = l & 15, h = l >> 4;
    const int base = blockIdx.x * 64;
    const int bb = (w & 3) * 16 + c;          // block-local batch 0..63
    const int batch = base + bb;
    const bool isFwd = w < 4;
    const int side = isFwd ? 0 : 1;

    __shared__ __align__(16) float AB[2][64][TT];   // final log2-states (64 KB)
    __shared__ float salpha[64];
    __shared__ float gpart[64][8];

    // ---- E fragments (f16, named): A[row=16t+c][k(q,h,j)] ----
    T8(DECLE)
    if (isFwd) { T8(EINF) } else { T8(EINB) }

    // ---- seed B (same k-map), exact pow2 pre-normalize ----
    f16x8 B0, B1, B2, B3;
    int Mint;
    float mprev;
    {
        T8(DECLS)
        const size_t f511 = ((size_t)batch * SS + 511) * TT;
        if (isFwd) { T8(SEEDF) if (h == 3) S7[2] = 1.0f; }   // k=126 -> t=7,h=3,j=2
        else       { T8(SEEDB) }
        float smax = 0.f;
        T8(SMXT)
        smax = fmaxf(smax, __shfl_xor(smax, 16));
        smax = fmaxf(smax, __shfl_xor(smax, 32));
        Mint = ((__float_as_int(fmaxf(smax, 1e-30f)) >> 23) & 255) - 126;
        const float sc0 = __int_as_float((127 - Mint) << 23);   // exact 2^-s0
        mprev = smax * sc0;                                      // in (0.5, 1]
        u32 Pa0, Pa1, Pa2, Pa3, Pa4, Pa5, Pa6, Pa7;
        u32 Pb0, Pb1, Pb2, Pb3, Pb4, Pb5, Pb6, Pb7;
        T8(SPKT)
        u32x4 b0_ = {Pa0, Pb0, Pa1, Pb1}; u32x4 b1_ = {Pa2, Pb2, Pa3, Pb3};
        u32x4 b2_ = {Pa4, Pb4, Pa5, Pb5}; u32x4 b3_ = {Pa6, Pb6, Pa7, Pb7};
        B0 = __builtin_bit_cast(f16x8, b0_); B1 = __builtin_bit_cast(f16x8, b1_);
        B2 = __builtin_bit_cast(f16x8, b2_); B3 = __builtin_bit_cast(f16x8, b3_);
    }

    // ---- ef pointers + double-buffered staging in named regs ----
    const char* pef;
    int sstep;
    if constexpr (PRE) {
        pef = (const char*)efeat + 2 * (((size_t)batch * SS + (isFwd ? 0 : 510)) * TT) + 8 * h;
        sstep = isFwd ? (TT * 2) : -(TT * 2);
    } else {
        pef = (const char*)feats + 4 * (((size_t)batch * SS + (isFwd ? 0 : 510)) * TT) + 16 * h;
        sstep = isFwd ? (TT * 4) : -(TT * 4);
    }
    T8(DECLEF)
    LDALL(EA)     // pos 0 / 510
    LDALL(EB)     // pos 1 / 509

#pragma unroll 1
    for (int it = 0; it < 127; ++it) {        // steps 0..253
        MSTEP(EA)
        MSTEP(EB)
    }
    MSTEP(EA)                                  // step 254 (its reload is harmless)
    // step 255 = epilogue multiply; fwd folds ef[255] (in EB) post-log; bwd none.

    const float Mtotf = (float)Mint;
    {
        f32x4 vz = {0.f, 0.f, 0.f, 0.f};
        T8(DECLA)
        T8(MFQ0) T8(MFQ1) T8(MFQ2) T8(MFQ3)
        T8(EPIT)                                // D rows are true tag indices
    }
    __syncthreads();

    // ---- Z = LSE_tag(A + B) (log2 domain), 8 batches per wave ----
#pragma unroll 1
    for (int k8 = 0; k8 < 8; ++k8) {
        const int bq = w * 8 + k8;
        float v0 = AB[0][bq][l] + AB[1][bq][l];
        float v1 = AB[0][bq][l + 64] + AB[1][bq][l + 64];
        float mm = wave_max(fmaxf(v0, v1));
        float ss = wave_sum(ex2(v0 - mm) + ex2(v1 - mm));
        if (l == 0) salpha[bq] = (mm + lg2(ss)) * LN2;
    }

    // ---- gold path score: 8 threads per batch, 64 steps each ----
    {
        const int bbg = t & 63, ck = t >> 6;
        const int gb  = base + bbg;
        const int* tg = targets + gb * SS;
        const float* fb = feats + (size_t)gb * SS * TT;
        float gs = 0.f;
        const int i0 = ck * 64;
        int prev = (i0 == 0) ? START_TAG : tg[i0 - 1];
        for (int i = i0; i < i0 + 64; ++i) {
            int cur = tg[i];
            gs += trans[cur * TT + prev] + fb[(size_t)i * TT + cur];
            prev = cur;
        }
        if (ck == 7) gs += trans[STOP_TAG * TT + tg[SS - 1]];
        gpart[bbg][ck] = gs;
    }
    __syncthreads();

    if (t < 64) {
        float g = 0.f;
#pragma unroll
        for (int k = 0; k < 8; ++k) g += gpart[t][k];
        out[base + t] = g - salpha[t];
    }
}

extern "C" void kernel_launch(void* const* d_in, const int* in_sizes, int n_in,
                              void* d_out, int out_size, void* d_ws, size_t ws_size,
                              hipStream_t stream) {
    (void)in_sizes; (void)n_in; (void)out_size;
    const float* feats   = (const float*)d_in[0];
    const float* trans   = (const float*)d_in[1];
    const int*   targets = (const int*)d_in[2];
    float*       out     = (float*)d_out;

    const size_t efbytes = (size_t)256 * SS * TT * sizeof(__fp16);  // 33.5 MB
    if (d_ws && ws_size >= efbytes) {
        __fp16* ef = (__fp16*)d_ws;
        exp_feats_kernel<<<dim3(8192), dim3(256), 0, stream>>>(feats, ef);
        crf_chain_kernel<true><<<dim3(4), dim3(512), 0, stream>>>(feats, trans, targets, ef, out);
    } else {
        crf_chain_kernel<false><<<dim3(4), dim3(512), 0, stream>>>(feats, trans, targets,
                                                                   (const __fp16*)nullptr, out);
    }
}

// Round 8
// 518.112 us; speedup vs baseline: 1.2363x; 1.2363x over previous
//
#include <hip/hip_runtime.h>

#define TT 128
#define SS 512
#define START_TAG 126
#define STOP_TAG 127
#define LOG2E 1.4426950408889634f
#define LN2   0.6931471805599453f
#define CBITS 8

typedef float f32x4 __attribute__((ext_vector_type(4)));
typedef __fp16 h2    __attribute__((ext_vector_type(2)));
typedef unsigned int u32;
typedef unsigned int u32x2 __attribute__((ext_vector_type(2)));
typedef unsigned int u32x4 __attribute__((ext_vector_type(4)));

__device__ __forceinline__ float ex2(float x){ return __builtin_amdgcn_exp2f(x); }   // 2^x
__device__ __forceinline__ float lg2(float x){ return __builtin_amdgcn_logf(x); }    // log2
__device__ __forceinline__ float exn(float x){ return __builtin_amdgcn_exp2f(x*LOG2E); } // e^x
__device__ __forceinline__ long mk64(u32 lo, u32 hi){ u32x2 v = {lo, hi}; return __builtin_bit_cast(long, v); }
__device__ __forceinline__ u32 pkh(float a, float b){
    return __builtin_bit_cast(u32, __builtin_amdgcn_cvt_pkrtz(a, b));
}
template<bool HI>
__device__ __forceinline__ u32 pk8(float a, float b, u32 old){
    return (u32)__builtin_amdgcn_cvt_pk_fp8_f32(a, b, (int)old, HI);   // HI is imm
}
__device__ __forceinline__ float wave_max(float v) {
#pragma unroll
    for (int off = 32; off >= 1; off >>= 1) v = fmaxf(v, __shfl_xor(v, off));
    return v;
}
__device__ __forceinline__ float wave_sum(float v) {
#pragma unroll
    for (int off = 32; off >= 1; off >>= 1) v += __shfl_xor(v, off);
    return v;
}

// ---------------- pre-pass: ef[b][s][tag] = (f16) exp(feats) ----------------
__global__ __launch_bounds__(256) void exp_feats_kernel(
    const float* __restrict__ feats, __fp16* __restrict__ ef)
{
    size_t i = ((size_t)blockIdx.x * 256 + threadIdx.x) * 8;
    f32x4 a = *(const f32x4*)(feats + i);
    f32x4 b = *(const f32x4*)(feats + i + 4);
    u32x4 pk;
    pk[0] = pkh(exn(a[0]), exn(a[1]));
    pk[1] = pkh(exn(a[2]), exn(a[3]));
    pk[2] = pkh(exn(b[0]), exn(b[1]));
    pk[3] = pkh(exn(b[2]), exn(b[3]));
    *(u32x4*)(ef + i) = pk;
}

// E fragment builders (init-time only, fp8). k-map: k(q,h,j) = 32q + 16*(j>=4) + 4h + (j&3)
__device__ __forceinline__ long efrag_f(const float* p) {        // fwd: rows contiguous
    f32x4 a = *(const f32x4*)p;
    f32x4 b = *(const f32x4*)(p + 16);
    u32 lo = pk8<false>(exn(a[0]), exn(a[1]), 0); lo = pk8<true>(exn(a[2]), exn(a[3]), lo);
    u32 hi = pk8<false>(exn(b[0]), exn(b[1]), 0); hi = pk8<true>(exn(b[2]), exn(b[3]), hi);
    return mk64(lo, hi);
}
__device__ __forceinline__ long efrag_b(const float* p) {        // bwd: E^T, stride-TT
    u32 lo = pk8<false>(exn(p[0]), exn(p[TT]), 0); lo = pk8<true>(exn(p[2*TT]), exn(p[3*TT]), lo);
    const float* q = p + 16 * TT;
    u32 hi = pk8<false>(exn(q[0]), exn(q[TT]), 0); hi = pk8<true>(exn(q[2*TT]), exn(q[3*TT]), hi);
    return mk64(lo, hi);
}

// ---- macro lists: everything hot is a NAMED scalar (no C-arrays; R3/R4
// showed LLVM parks arrays in the AGPR half -> accvgpr churn). ----
#define T8(M)    M(0) M(1) M(2) M(3) M(4) M(5) M(6) M(7)
#define T8P(M,P) M(0,P) M(1,P) M(2,P) M(3,P) M(4,P) M(5,P) M(6,P) M(7,P)

#define DECLE(t)  long E0##t, E1##t, E2##t, E3##t;
#define DECLEF(t) u32x2 EA##t, EB##t, EC##t;
#define DECLS(t)  f32x4 S##t;
#define DECLAX(t) f32x4 AX##t;
#define DECLAY(t) f32x4 AY##t;

#define MFI(t,AN)  AN##t = __builtin_amdgcn_mfma_f32_16x16x32_fp8_fp8(E0##t, B0, vz,    0, 0, 0);
#define MFA1(t,AN) AN##t = __builtin_amdgcn_mfma_f32_16x16x32_fp8_fp8(E1##t, B1, AN##t, 0, 0, 0);
#define MFA2(t,AN) AN##t = __builtin_amdgcn_mfma_f32_16x16x32_fp8_fp8(E2##t, B2, AN##t, 0, 0, 0);
#define MFA3(t,AN) AN##t = __builtin_amdgcn_mfma_f32_16x16x32_fp8_fp8(E3##t, B3, AN##t, 0, 0, 0);

// pack one D-tile: scale (exact 2^-s) -> emission (prepassed f16 ef) -> fp8.
// colmax tracked post-emission in f32 (bounds the packed values; R6-validated).
#define PKT(t, AC, RR) { \
    h2 ea_ = __builtin_bit_cast(h2, RR##t[0]); h2 eb_ = __builtin_bit_cast(h2, RR##t[1]); \
    float d0 = AC##t[0]*scf*(float)ea_[0], d1 = AC##t[1]*scf*(float)ea_[1]; \
    float d2 = AC##t[2]*scf*(float)eb_[0], d3 = AC##t[3]*scf*(float)eb_[1]; \
    mloc = fmaxf(fmaxf(mloc, fmaxf(d0, d1)), fmaxf(d2, d3)); \
    u32 r_ = pk8<false>(d0, d1, 0); P##t = pk8<true>(d2, d3, r_); }

#define LDRT(t, RR) { if constexpr (PRE) { RR##t = *(const u32x2*)(pef + 32*(t)); } \
    else { f32x4 v_ = *(const f32x4*)(pef + 64*(t)); \
           RR##t[0] = pkh(exn(v_[0]), exn(v_[1])); RR##t[1] = pkh(exn(v_[2]), exn(v_[3])); } }
#define LDALL(RR) { T8P(LDRT, RR) pef += sstep; }

// One pipelined recurrence iteration: pack(D_i in AC, ef_i in RR) phase-by-phase,
// each B-chunk q immediately feeds its 8 MFMAs into AN (D_{i+1}). VALU pack of
// phase q+1 overlaps MFMA pipe of phase q -> MFMA-bound step (~650 cy target).
// Scale 2^-s from LAG-1 post-scale colmax (stable; validated R3/R4/R6).
#define STEP(AC, AN, RR) { \
    int s_ = ((__float_as_int(fmaxf(mprev, 1e-30f)) >> 23) & 255) - 126 + CBITS; \
    s_ = s_ < -120 ? -120 : (s_ > 120 ? 120 : s_); \
    Mint += s_; \
    const float scf = __int_as_float((127 - s_) << 23); \
    f32x4 vz = {0.f, 0.f, 0.f, 0.f}; \
    float mloc = 0.f; \
    u32 P0, P1, P2, P3, P4, P5, P6, P7; \
    PKT(0, AC, RR) PKT(1, AC, RR) long B0 = mk64(P0, P1); \
    T8P(MFI,  AN) \
    PKT(2, AC, RR) PKT(3, AC, RR) long B1 = mk64(P2, P3); \
    T8P(MFA1, AN) \
    PKT(4, AC, RR) PKT(5, AC, RR) long B2 = mk64(P4, P5); \
    T8P(MFA2, AN) \
    PKT(6, AC, RR) PKT(7, AC, RR) long B3 = mk64(P6, P7); \
    T8P(MFA3, AN) \
    mloc = fmaxf(mloc, __shfl_xor(mloc, 16)); \
    mloc = fmaxf(mloc, __shfl_xor(mloc, 32)); \
    mprev = mloc; \
    LDALL(RR) }

#define EINF(t) { const float* rp = trans + (16*(t) + c) * TT + 4 * h; \
    E0##t = efrag_f(rp); E1##t = efrag_f(rp + 32); E2##t = efrag_f(rp + 64); E3##t = efrag_f(rp + 96); }
#define EINB(t) { const float* cp = trans + (4 * h) * TT + 16*(t) + c; \
    E0##t = efrag_b(cp); E1##t = efrag_b(cp + 32*TT); E2##t = efrag_b(cp + 64*TT); E3##t = efrag_b(cp + 96*TT); }

#define SEEDF(t) S##t = (f32x4){0.f, 0.f, 0.f, 0.f};
#define SEEDB(t) { \
    f32x4 tr4 = *(const f32x4*)(trans + STOP_TAG * TT + 16*(t) + 4*h); \
    f32x4 fe4 = *(const f32x4*)(feats + f511 + 16*(t) + 4*h); \
    S##t[0] = exn(tr4[0] + fe4[0]); S##t[1] = exn(tr4[1] + fe4[1]); \
    S##t[2] = exn(tr4[2] + fe4[2]); S##t[3] = exn(tr4[3] + fe4[3]); }
#define SMXT(t) smax = fmaxf(smax, fmaxf(fmaxf(S##t[0], S##t[1]), fmaxf(S##t[2], S##t[3])));
#define SPKT(t) { u32 r_ = pk8<false>(S##t[0]*sc0, S##t[1]*sc0, 0); \
    P##t = pk8<true>(S##t[2]*sc0, S##t[3]*sc0, r_); }

// epilogue: D_255 in AY; fwd folds ef[255] (in EA) post-log; bwd none.
#define EPIT(t) { f32x4 v; \
    float e0 = 1.f, e1 = 1.f, e2 = 1.f, e3 = 1.f; \
    if (isFwd) { h2 a = __builtin_bit_cast(h2, EA##t[0]); h2 b = __builtin_bit_cast(h2, EA##t[1]); \
                 e0 = (float)a[0]; e1 = (float)a[1]; e2 = (float)b[0]; e3 = (float)b[1]; } \
    v[0] = Mtotf + lg2(fmaxf(AY##t[0] * e0, 1e-35f)); \
    v[1] = Mtotf + lg2(fmaxf(AY##t[1] * e1, 1e-35f)); \
    v[2] = Mtotf + lg2(fmaxf(AY##t[2] * e2, 1e-35f)); \
    v[3] = Mtotf + lg2(fmaxf(AY##t[3] * e3, 1e-35f)); \
    *(f32x4*)&AB[side][bb][16*(t) + 4*h] = v; }

// 8 blocks x 256 threads (1 wave/SIMD; R7 proved 2 phase-locked waves/SIMD
// give exactly zero overlap). Block k: batches 32k..32k+31.
//  w0: fwd chains (+0..15)  w1: fwd (+16..31)  w2: bwd (+0..15)  w3: bwd (+16..31)
template<bool PRE>
__global__ __launch_bounds__(256, 2) void crf_chain_kernel(
    const float* __restrict__ feats,
    const float* __restrict__ trans,
    const int*   __restrict__ targets,
    const __fp16* __restrict__ efeat,
    float*       __restrict__ out)
{
    const int t = threadIdx.x;
    const int w = t >> 6, l = t & 63;
    const int c = l & 15, h = l >> 4;
    const int base = blockIdx.x * 32;
    const int bb = (w & 1) * 16 + c;          // block-local batch 0..31
    const int batch = base + bb;
    const bool isFwd = (w >> 1) == 0;
    const int side = isFwd ? 0 : 1;

    __shared__ __align__(16) float AB[2][32][TT];   // final log2-states
    __shared__ float salpha[32];
    __shared__ float gpart[32][8];

    // ---- E fragments (fp8, named): A[row=16t+c][k(q,h,j)] ----
    T8(DECLE)
    if (isFwd) { T8(EINF) } else { T8(EINB) }

    // ---- ef pointers + depth-3 staging in named regs ----
    const char* pef;
    int sstep;
    if constexpr (PRE) {
        pef = (const char*)efeat + 2 * (((size_t)batch * SS + (isFwd ? 0 : 510)) * TT) + 8 * h;
        sstep = isFwd ? (TT * 2) : -(TT * 2);
    } else {
        pef = (const char*)feats + 4 * (((size_t)batch * SS + (isFwd ? 0 : 510)) * TT) + 16 * h;
        sstep = isFwd ? (TT * 4) : -(TT * 4);
    }
    T8(DECLEF)
    LDALL(EA)     // pos 0 / 510
    LDALL(EB)     // pos 1 / 509
    LDALL(EC)     // pos 2 / 508

    // ---- seed B (same k-map), exact pow2 pre-normalize; prologue MFMA -> AX=D_0 ----
    T8(DECLAX) T8(DECLAY)
    int Mint;
    float mprev;
    {
        T8(DECLS)
        const size_t f511 = ((size_t)batch * SS + 511) * TT;
        if (isFwd) { T8(SEEDF) if (h == 3) S7[2] = 1.0f; }   // k=126 -> t=7,h=3,j=2
        else       { T8(SEEDB) }
        float smax = 0.f;
        T8(SMXT)
        smax = fmaxf(smax, __shfl_xor(smax, 16));
        smax = fmaxf(smax, __shfl_xor(smax, 32));
        Mint = ((__float_as_int(fmaxf(smax, 1e-30f)) >> 23) & 255) - 126;
        const float sc0 = __int_as_float((127 - Mint) << 23);   // exact 2^-s0
        mprev = smax * sc0;                                      // in (0.5, 1]
        u32 P0, P1, P2, P3, P4, P5, P6, P7;
        T8(SPKT)
        long B0 = mk64(P0, P1), B1 = mk64(P2, P3), B2 = mk64(P4, P5), B3 = mk64(P6, P7);
        f32x4 vz = {0.f, 0.f, 0.f, 0.f};
        T8P(MFI,  AX)
        T8P(MFA1, AX)
        T8P(MFA2, AX)
        T8P(MFA3, AX)
    }

    // ---- 255 pipelined iterations: D_i -> D_{i+1}. LCM(A-parity=2, ef-depth=3)=6. ----
#pragma unroll 1
    for (int it = 0; it < 42; ++it) {         // iterations 0..251
        STEP(AX, AY, EA)
        STEP(AY, AX, EB)
        STEP(AX, AY, EC)
        STEP(AY, AX, EA)
        STEP(AX, AY, EB)
        STEP(AY, AX, EC)
    }
    STEP(AX, AY, EA)                           // it 252 (reloads EA <- ef[255])
    STEP(AY, AX, EB)                           // it 253 (junk reload, in-bounds)
    STEP(AX, AY, EC)                           // it 254 (junk reload, in-bounds)
    // D_255 now in AY; ef[255] in EA.

    const float Mtotf = (float)Mint;
    { T8(EPIT) }                               // D rows are true tag indices
    __syncthreads();

    // ---- Z = LSE_tag(A + B) (log2 domain), 8 batches per wave ----
#pragma unroll 1
    for (int k8 = 0; k8 < 8; ++k8) {
        const int bq = w * 8 + k8;
        float v0 = AB[0][bq][l] + AB[1][bq][l];
        float v1 = AB[0][bq][l + 64] + AB[1][bq][l + 64];
        float mm = wave_max(fmaxf(v0, v1));
        float ss = wave_sum(ex2(v0 - mm) + ex2(v1 - mm));
        if (l == 0) salpha[bq] = (mm + lg2(ss)) * LN2;
    }

    // ---- gold path score: 8 threads per batch, 64 steps each ----
    {
        const int bbg = t & 31, ck = t >> 5;
        const int gb  = base + bbg;
        const int* tg = targets + gb * SS;
        const float* fb = feats + (size_t)gb * SS * TT;
        float gs = 0.f;
        const int i0 = ck * 64;
        int prev = (i0 == 0) ? START_TAG : tg[i0 - 1];
        for (int i = i0; i < i0 + 64; ++i) {
            int cur = tg[i];
            gs += trans[cur * TT + prev] + fb[(size_t)i * TT + cur];
            prev = cur;
        }
        if (ck == 7) gs += trans[STOP_TAG * TT + tg[SS - 1]];
        gpart[bbg][ck] = gs;
    }
    __syncthreads();

    if (t < 32) {
        float g = 0.f;
#pragma unroll
        for (int k = 0; k < 8; ++k) g += gpart[t][k];
        out[base + t] = g - salpha[t];
    }
}

extern "C" void kernel_launch(void* const* d_in, const int* in_sizes, int n_in,
                              void* d_out, int out_size, void* d_ws, size_t ws_size,
                              hipStream_t stream) {
    (void)in_sizes; (void)n_in; (void)out_size;
    const float* feats   = (const float*)d_in[0];
    const float* trans   = (const float*)d_in[1];
    const int*   targets = (const int*)d_in[2];
    float*       out     = (float*)d_out;

    const size_t efbytes = (size_t)256 * SS * TT * sizeof(__fp16);  // 33.5 MB
    if (d_ws && ws_size >= efbytes) {
        __fp16* ef = (__fp16*)d_ws;
        exp_feats_kernel<<<dim3(8192), dim3(256), 0, stream>>>(feats, ef);
        crf_chain_kernel<true><<<dim3(8), dim3(256), 0, stream>>>(feats, trans, targets, ef, out);
    } else {
        crf_chain_kernel<false><<<dim3(8), dim3(256), 0, stream>>>(feats, trans, targets,
                                                                   (const __fp16*)nullptr, out);
    }
}